// Round 7
// baseline (862.512 us; speedup 1.0000x reference)
//
#include <hip/hip_runtime.h>
#include <hip/hip_bf16.h>
#include <math.h>

#define BB   8
#define SS   256
#define DD   512
#define NHH  8
#define HDD  64
#define EE   4
#define LL   2
#define FFF  2048
#define RHH  256
#define VV   32000
#define MVV  2
#define TOK  (BB*SS)   // 2048
#define CASTBLK 44672

typedef __attribute__((ext_vector_type(8))) short bf16x8;
typedef __attribute__((ext_vector_type(4))) float f32x4;

// ---------------- helpers ----------------
__device__ __forceinline__ float wred_sum(float v){
#pragma unroll
  for(int o=32;o;o>>=1) v += __shfl_xor(v,o,64);
  return v;
}
__device__ __forceinline__ float block_sum(float v, float* sh){
  v = wred_sum(v);
  if((threadIdx.x&63)==0) sh[threadIdx.x>>6]=v;
  __syncthreads();
  float t = sh[0]+sh[1]+sh[2]+sh[3];
  __syncthreads();
  return t;
}
__device__ __forceinline__ float gelu_exact(float x){
  return 0.5f*x*(1.f+erff(x*0.70710678118654752f));
}
__device__ __forceinline__ unsigned short bfr(float f){
  union{float f; unsigned u;} c; c.f=f;
  unsigned u = c.u;
  return (unsigned short)((u + 0x7FFFu + ((u>>16)&1u)) >> 16);
}

// ---------------- fused: weight casts + embed+PE+LN ----------------
__global__ void k_preproc(const float* __restrict__ s0,const float* __restrict__ s1,
                          const float* __restrict__ s2,const float* __restrict__ s3,
                          const float* __restrict__ s4,const float* __restrict__ s5,
                          unsigned short* __restrict__ d0,unsigned short* __restrict__ d1,
                          unsigned short* __restrict__ d2,unsigned short* __restrict__ d3,
                          unsigned short* __restrict__ d4,unsigned short* __restrict__ d5,
                          const int* __restrict__ ids, const float* __restrict__ emb,
                          float* __restrict__ x){
  __shared__ float sh[4];
  if(blockIdx.x < CASTBLK){
    long i = (long)blockIdx.x*256 + threadIdx.x;
    const float* s; unsigned short* d; long o;
    if(i < 1572864L){ s=s0; d=d0; o=i; }
    else if(i < 2097152L){ s=s1; d=d1; o=i-1572864L; }
    else if(i < 3145728L){ s=s2; d=d2; o=i-2097152L; }
    else if(i < 5242880L){ s=s3; d=d3; o=i-3145728L; }
    else if(i < 7340032L){ s=s4; d=d4; o=i-5242880L; }
    else { s=s5; d=d5; o=i-7340032L; }
    float4 v = ((const float4*)s)[o];
    ushort4 u; u.x=bfr(v.x); u.y=bfr(v.y); u.z=bfr(v.z); u.w=bfr(v.w);
    ((ushort4*)d)[o] = u;
    return;
  }
  int tok = blockIdx.x - CASTBLK;
  int s = tok & (SS-1);
  int tid = threadIdx.x;
  int id = ids[tok];
  float v[2];
#pragma unroll
  for(int i=0;i<2;i++){
    int d = tid + i*256;
    float e = emb[(size_t)id*DD + d] * 22.627416997969522f; // sqrt(512)
    int j = d >> 1;
    float freq = expf((float)(2*j) * (-0.0179889460390160f)); // -ln(1e4)/512
    float arg = (float)s * freq;
    v[i] = e + ((d & 1) ? cosf(arg) : sinf(arg));
  }
  float m = block_sum(v[0]+v[1], sh) * (1.f/DD);
  float dd0=v[0]-m, dd1=v[1]-m;
  float var = block_sum(dd0*dd0+dd1*dd1, sh) * (1.f/DD);
  float inv = rsqrtf(var + 1e-5f);
  float* q = x + (size_t)tok*DD;
  q[tid] = dd0*inv; q[tid+256] = dd1*inv;
}

// ---------------- combine(+x ping-pong) + LN + optional psum ----------------
__global__ void k_lnpsum(const float* __restrict__ xin, const float* __restrict__ P0,
                         const float* __restrict__ P1, float* __restrict__ xout,
                         float* __restrict__ zf, unsigned short* __restrict__ zb,
                         float* __restrict__ psum, const int* __restrict__ dof){
  __shared__ float sh[4];
  int tid = threadIdx.x;
  if(blockIdx.x < TOK){
    int tok = blockIdx.x; int b = tok>>8;
    size_t base = (size_t)tok*DD;
    float a0 = xin[base+tid], a1 = xin[base+tid+256];
    if(P0){
      if(dof[b]){
        a0 += P0[base+tid]     + P1[base+tid];
        a1 += P0[base+tid+256] + P1[base+tid+256];
      }
      xout[base+tid] = a0; xout[base+tid+256] = a1;
    }
    float m = block_sum(a0+a1, sh) * (1.f/DD);
    float d0=a0-m, d1=a1-m;
    float var = block_sum(d0*d0+d1*d1, sh) * (1.f/DD);
    float inv = rsqrtf(var + 1e-5f);
    zf[base+tid] = d0*inv; zf[base+tid+256] = d1*inv;
    zb[base+tid] = bfr(d0*inv); zb[base+tid+256] = bfr(d1*inv);
  } else {
    int pb = blockIdx.x - TOK; int b = pb>>4, p = pb&15;
    bool c = (P0 != nullptr) && dof[b];
    float s0=0.f, s1=0.f;
    for(int tt=0; tt<16; tt++){
      size_t r = (size_t)(b*SS + p*16 + tt)*DD;
      float v0 = xin[r+tid], v1 = xin[r+tid+256];
      if(c){ v0 += P0[r+tid]+P1[r+tid]; v1 += P0[r+tid+256]+P1[r+tid+256]; }
      s0 += v0; s1 += v1;
    }
    float* q = psum + (size_t)(b*16+p)*DD;
    q[tid] = s0; q[tid+256] = s1;
  }
}

// ---------------- router (reduces psum partials) ----------------
__global__ void k_router(const float* __restrict__ psum,
                         const float* __restrict__ r_w1, const float* __restrict__ r_b1,
                         const float* __restrict__ r_w2, const float* __restrict__ r_b2,
                         const float* __restrict__ r_q,
                         int* __restrict__ action, int* __restrict__ dof,
                         int* __restrict__ visits, int* __restrict__ active, int step){
  int b = blockIdx.x; int tid = threadIdx.x;
  if(step==0 && tid==0){ active[b]=1; for(int e=0;e<EE;e++) visits[b*EE+e]=0; }
  __shared__ float ssum[DD];
  __shared__ float hid[RHH];
  __shared__ float lg[EE+1];
  float s0=0.f, s1=0.f;
  for(int p=0;p<16;p++){
    const float* q = psum + (size_t)(b*16+p)*DD;
    s0 += q[tid]; s1 += q[tid+256];
  }
  ssum[tid] = s0*(1.f/SS); ssum[tid+256] = s1*(1.f/SS);
  __syncthreads();
  float acc = r_b1[tid];
  const float4* wr4 = (const float4*)(r_w1 + (size_t)tid*DD);
  for(int d4=0; d4<DD/4; d4++){
    float4 wv = wr4[d4];
    float4 sv = *(const float4*)&ssum[d4*4];
    acc += wv.x*sv.x + wv.y*sv.y + wv.z*sv.z + wv.w*sv.w;
  }
  hid[tid] = gelu_exact(acc);
  __syncthreads();
  if(tid < EE+1){
    const float* w2 = r_w2 + (size_t)tid*RHH;
    float a = r_b2[tid] + r_q[tid];
    for(int j=0;j<RHH;j++) a += hid[j]*w2[j];
    lg[tid]=a;
  }
  __syncthreads();
  if(tid==0){
    float m=0.f; for(int k=0;k<EE+1;k++) m+=lg[k]; m *= (1.f/(EE+1));
    float v=0.f; for(int k=0;k<EE+1;k++){float d=lg[k]-m; v+=d*d;} v *= (1.f/(EE+1));
    float inv = rsqrtf(v+1e-5f);
    float best=-1e38f; int bi=0;
    for(int k=0;k<EE+1;k++){
      float fl = (lg[k]-m)*inv;
      fl = fminf(fmaxf(fl,-10.f),10.f);
      if(k<EE && visits[b*EE+k]>=MVV) fl = -1e38f;
      if(fl > best){best=fl; bi=k;}
    }
    int dd = (active[b] && bi<EE) ? 1 : 0;
    action[b]=bi; dof[b]=dd;
    if(dd) visits[b*EE+bi]++;
    active[b]=dd;
  }
}

// ---------------- generic 64x128 MFMA GEMM core, BK=64, 2-phase dbuf ----------------
template<int EPI>
__device__ __forceinline__ void mg64(
    unsigned short* sA, unsigned short* sW,
    const unsigned short* __restrict__ A, int Ald,
    const unsigned short* __restrict__ W, int Wld,
    const float* __restrict__ bias, const float* __restrict__ tagv,
    int N, int K,
    float* __restrict__ Cf, unsigned short* __restrict__ Cb,
    int rowbase, int colbase){
  int t = threadIdx.x;
  int lane = t & 63;
  int w = t >> 6;
  int wcol0 = w*32;
  int sr = t >> 3, ss8 = t & 7;

  f32x4 acc[4][2];
#pragma unroll
  for(int m=0;m<4;m++)
#pragma unroll
    for(int n=0;n<2;n++) acc[m][n] = (f32x4){0.f,0.f,0.f,0.f};

  auto STAGE = [&](int buf, int k0){
    unsigned short* dA = sA + buf*4096;
    unsigned short* dW = sW + buf*8192;
#pragma unroll
    for(int i = 0; i < 2; i++){
      int r  = i*32 + sr;
      int ce = ((ss8<<4) ^ ((r&7)<<4)) >> 1;
      const unsigned short* gp = A + (size_t)(rowbase + r)*Ald + k0 + ce;
      __builtin_amdgcn_global_load_lds((const __attribute__((address_space(1))) void*)gp,
          (__attribute__((address_space(3))) void*)(dA + i*2048 + t*8), 16, 0, 0);
    }
#pragma unroll
    for(int i = 0; i < 4; i++){
      int r  = i*32 + sr;
      int ce = ((ss8<<4) ^ ((r&7)<<4)) >> 1;
      const unsigned short* gw = W + (size_t)(colbase + r)*Wld + k0 + ce;
      __builtin_amdgcn_global_load_lds((const __attribute__((address_space(1))) void*)gw,
          (__attribute__((address_space(3))) void*)(dW + i*2048 + t*8), 16, 0, 0);
    }
  };

  STAGE(0, 0);
  int cur = 0;
  for(int k0 = 0; k0 < K; k0 += 64){
    if(k0 + 64 < K){
      STAGE(cur^1, k0+64);
      asm volatile("s_waitcnt vmcnt(6)" ::: "memory");
    } else {
      asm volatile("s_waitcnt vmcnt(0)" ::: "memory");
    }
    __builtin_amdgcn_s_barrier();
    __builtin_amdgcn_sched_barrier(0);
    const char* bA = (const char*)(sA + cur*4096);
    const char* bW = (const char*)(sW + cur*8192);
#pragma unroll
    for(int ks = 0; ks < 2; ks++){
      bf16x8 af[4], wf[2];
#pragma unroll
      for(int m = 0; m < 4; m++){
        int r = m*16 + (lane & 15);
        af[m] = *(const bf16x8*)(bA + r*128 + (((((lane>>4)<<4)|(ks<<6))) ^ ((r&7)<<4)));
      }
#pragma unroll
      for(int n = 0; n < 2; n++){
        int r = wcol0 + n*16 + (lane & 15);
        wf[n] = *(const bf16x8*)(bW + r*128 + (((((lane>>4)<<4)|(ks<<6))) ^ ((r&7)<<4)));
      }
#pragma unroll
      for(int m = 0; m < 4; m++)
#pragma unroll
        for(int n = 0; n < 2; n++)
          acc[m][n] = __builtin_amdgcn_mfma_f32_16x16x32_bf16(af[m], wf[n], acc[m][n], 0, 0, 0);
    }
    asm volatile("s_waitcnt lgkmcnt(0)" ::: "memory");
    __builtin_amdgcn_s_barrier();
    cur ^= 1;
  }
  int orow0 = rowbase + ((lane >> 4) << 2);
  int ocol0 = colbase + wcol0 + (lane & 15);
#pragma unroll
  for(int m = 0; m < 4; m++){
#pragma unroll
    for(int n = 0; n < 2; n++){
      int col = ocol0 + n*16;
      float addv = (bias ? bias[col] : 0.f) + (tagv ? tagv[col] : 0.f);
#pragma unroll
      for(int j = 0; j < 4; j++){
        int row = orow0 + m*16 + j;
        size_t idx = (size_t)row*N + col;
        float v = acc[m][n][j] + addv;
        if(EPI == 0){ if(Cf) Cf[idx] = v; if(Cb) Cb[idx] = bfr(v); }
        else if(EPI == 1){ Cb[idx] = bfr(gelu_exact(v)); }
        else { Cf[idx] += v; }
      }
    }
  }
}

#define GEMM_LDS __shared__ unsigned short sA[2*64*64]; __shared__ unsigned short sW[2*128*64];

// qkv (z<12) + gate z-half (z>=12), both read z_bf, K=512
__global__ __launch_bounds__(256)
void k_qkvgate(const unsigned short* __restrict__ z_bf,
               const unsigned short* __restrict__ in_wb, const float* __restrict__ in_b,
               const unsigned short* __restrict__ gate_wb, const float* __restrict__ gate_b,
               unsigned short* __restrict__ qkv_bf, float* __restrict__ gtmp, int l,
               const int* __restrict__ action, const int* __restrict__ dof){
  GEMM_LDS
  int b = blockIdx.x; if(!dof[b]) return;
  size_t o = (size_t)(action[b]*LL + l);
  int rowbase = b*SS + blockIdx.y*64;
  int zz = blockIdx.z;
  if(zz < 12){
    mg64<0>(sA,sW, z_bf,DD, in_wb + o*3*DD*DD, DD, in_b + o*3*DD, nullptr,
            3*DD, DD, nullptr, qkv_bf, rowbase, zz*128);
  } else {
    mg64<0>(sA,sW, z_bf,DD, gate_wb + o*DD*2*DD, 2*DD, gate_b + o*DD, nullptr,
            DD, DD, gtmp, nullptr, rowbase, (zz-12)*128);
  }
}

// ---- fused out-proj + gate(ao-half) + gated-residual + LN2, no-LDS direct-frag GEMMs ----
// grid: TOK/16 blocks, 256 threads (4 waves). Wave w owns cols w*128..+128.
__global__ __launch_bounds__(256)
void k_outgate(const unsigned short* __restrict__ attno_bf,
               const unsigned short* __restrict__ out_wb, const float* __restrict__ out_b,
               const unsigned short* __restrict__ gate_wb,
               const float* __restrict__ gtmp, const float* __restrict__ z,
               float* __restrict__ x, unsigned short* __restrict__ z2b, int lyr,
               const int* __restrict__ action, const int* __restrict__ dof){
  int r0 = blockIdx.x*16;
  int b = r0 >> 8; if(!dof[b]) return;
  size_t o = (size_t)(action[b]*LL + lyr);
  const unsigned short* Wo = out_wb  + o*DD*DD;            // [512][512]
  const unsigned short* Wa = gate_wb + o*DD*2*DD;          // [512][1024], ao-half at k+512
  const float* bias = out_b + o*DD;
  __shared__ unsigned short sAO[16*512];                   // 16KB, XOR-swizzled
  __shared__ float sred[4][16][2];
  int t = threadIdx.x, l = t&63, w = t>>6;
  int lr = l & 15;           // fragment row/col index
  int lk = (l>>4)*8;         // fragment k element offset
  int c0 = w*128;

  // Phase A: ao = attno @ Wo^T  (direct global fragment reads, no barriers)
  f32x4 accA[8];
#pragma unroll
  for(int cf=0;cf<8;cf++) accA[cf] = (f32x4){0.f,0.f,0.f,0.f};
  for(int k0=0;k0<DD;k0+=32){
    bf16x8 af = *(const bf16x8*)(attno_bf + (size_t)(r0+lr)*DD + k0 + lk);
#pragma unroll
    for(int cf=0;cf<8;cf++){
      bf16x8 wf = *(const bf16x8*)(Wo + (size_t)(c0+cf*16+lr)*DD + k0 + lk);
      accA[cf] = __builtin_amdgcn_mfma_f32_16x16x32_bf16(af, wf, accA[cf], 0, 0, 0);
    }
  }
  // park ao (bf16, swizzled) in LDS as K-operand for phase B
#pragma unroll
  for(int cf=0;cf<8;cf++){
    int col = c0 + cf*16 + lr;
    float bv = bias[col];
#pragma unroll
    for(int j=0;j<4;j++){
      int row = ((l>>4)<<2) + j;
      float ao = accA[cf][j] + bv;
      accA[cf][j] = ao;   // keep biased value for elementwise use
      *(unsigned short*)((char*)sAO + row*1024 + ((col*2) ^ ((row&7)<<4))) = bfr(ao);
    }
  }
  __syncthreads();

  // Phase B: gate ao-half: ga = ao @ Wa[:,512:]^T  (A from LDS, W direct)
  f32x4 accB[8];
#pragma unroll
  for(int cf=0;cf<8;cf++) accB[cf] = (f32x4){0.f,0.f,0.f,0.f};
  for(int k0=0;k0<DD;k0+=32){
    bf16x8 af = *(const bf16x8*)((const char*)sAO + lr*1024 + (((k0+lk)*2) ^ ((lr&7)<<4)));
#pragma unroll
    for(int cf=0;cf<8;cf++){
      bf16x8 wf = *(const bf16x8*)(Wa + (size_t)(c0+cf*16+lr)*1024 + 512 + k0 + lk);
      accB[cf] = __builtin_amdgcn_mfma_f32_16x16x32_bf16(af, wf, accB[cf], 0, 0, 0);
    }
  }

  // elementwise: t = z + sigmoid(gz + ga) * ao ; accumulate row sums
  float tv[8][4];
  float rs[4] = {0.f,0.f,0.f,0.f}, rq[4] = {0.f,0.f,0.f,0.f};
#pragma unroll
  for(int cf=0;cf<8;cf++){
    int col = c0 + cf*16 + lr;
#pragma unroll
    for(int j=0;j<4;j++){
      int row = r0 + ((l>>4)<<2) + j;
      float g = accB[cf][j] + gtmp[(size_t)row*DD + col];
      float sig = 1.f/(1.f+expf(-g));
      float v = z[(size_t)row*DD + col] + sig*accA[cf][j];
      tv[cf][j] = v; rs[j] += v; rq[j] += v*v;
    }
  }
  // reduce over the 16 lanes holding this wave's cols
#pragma unroll
  for(int j=0;j<4;j++){
#pragma unroll
    for(int of=1;of<16;of<<=1){ rs[j] += __shfl_xor(rs[j],of,64); rq[j] += __shfl_xor(rq[j],of,64); }
  }
  if(lr==0){
#pragma unroll
    for(int j=0;j<4;j++){
      int row = ((l>>4)<<2) + j;
      sred[w][row][0] = rs[j]; sred[w][row][1] = rq[j];
    }
  }
  __syncthreads();
  // finalize LN per row, write x (in place) and z2_bf
#pragma unroll
  for(int j=0;j<4;j++){
    int row = ((l>>4)<<2) + j;
    float s = sred[0][row][0]+sred[1][row][0]+sred[2][row][0]+sred[3][row][0];
    float q = sred[0][row][1]+sred[1][row][1]+sred[2][row][1]+sred[3][row][1];
    float m = s*(1.f/DD);
    float var = q*(1.f/DD) - m*m;
    float inv = rsqrtf(var + 1e-5f);
    int grow = r0 + row;
#pragma unroll
    for(int cf=0;cf<8;cf++){
      int col = c0 + cf*16 + lr;
      float nt = (tv[cf][j]-m)*inv;
      size_t idx = (size_t)grow*DD + col;
      x[idx] += nt;
      z2b[idx] = bfr(x[idx] - x[idx] + nt); // nt in bf16
    }
  }
}

// ffn1: ffh = gelu(z2 @ w1^T + b1)
__global__ __launch_bounds__(256)
void k_ffn1(const unsigned short* __restrict__ z2_bf,
            const unsigned short* __restrict__ f_w1b, const float* __restrict__ f_b1,
            unsigned short* __restrict__ ffh_bf, int l,
            const int* __restrict__ action, const int* __restrict__ dof){
  GEMM_LDS
  int b = blockIdx.x; if(!dof[b]) return;
  size_t o = (size_t)(action[b]*LL + l);
  mg64<1>(sA,sW, z2_bf,DD, f_w1b + o*FFF*DD, DD, f_b1 + o*FFF, nullptr,
          FFF, DD, nullptr, ffh_bf, b*SS + blockIdx.y*64, blockIdx.z*128);
}

// ffn2 split-K: half 0 -> P0 (+bias +tag at l==1), half 1 -> P1
__global__ __launch_bounds__(256)
void k_ffn2(const unsigned short* __restrict__ ffh_bf,
            const unsigned short* __restrict__ f_w2b, const float* __restrict__ f_b2,
            const float* __restrict__ tag,
            float* __restrict__ P0, float* __restrict__ P1, int l,
            const int* __restrict__ action, const int* __restrict__ dof){
  GEMM_LDS
  int b = blockIdx.x; if(!dof[b]) return;
  size_t o = (size_t)(action[b]*LL + l);
  int half = blockIdx.z >> 2, colb = (blockIdx.z & 3)*128;
  const float* bias = half ? nullptr : (f_b2 + o*DD);
  const float* tagv = (half==0 && l==LL-1) ? (tag + (size_t)action[b]*DD) : nullptr;
  mg64<0>(sA,sW, ffh_bf + half*1024, FFF, f_w2b + o*DD*FFF + half*1024, FFF,
          bias, tagv, DD, 1024, half ? P1 : P0, nullptr,
          b*SS + blockIdx.y*64, colb);
}

// ---------------- fused attention: softmax(QK^T/8) @ V, bf16 MFMA ----------------
__global__ __launch_bounds__(256)
void k_attn(const unsigned short* __restrict__ qkv, unsigned short* __restrict__ attno,
            const int* __restrict__ dof){
  int bh = blockIdx.x; int b = bh>>3, h = bh&7;
  if(!dof[b]) return;
  int q0 = blockIdx.y*64;
  __shared__ unsigned short sK[256*64];   // 32KB; reused as P after scores
  __shared__ unsigned short sVT[64*256];  // 32KB, V transposed [d][k]
  int t = threadIdx.x, l = t&63, w = t>>6;
  const unsigned short* qbase = qkv + (size_t)b*SS*1536;

  {
    int sr = t>>3, s8 = t&7;
#pragma unroll
    for(int i=0;i<8;i++){
      int r = i*32 + sr;
      int ce = ((s8<<4) ^ ((r&7)<<4)) >> 1;
      const unsigned short* gp = qbase + (size_t)r*1536 + 512 + h*64 + ce;
      __builtin_amdgcn_global_load_lds((const __attribute__((address_space(1))) void*)gp,
          (__attribute__((address_space(3))) void*)(sK + i*2048 + t*8), 16, 0, 0);
    }
  }
  {
    int kt0 = t>>2, dg = (t&3)*16;
#pragma unroll
    for(int i=0;i<4;i++){
      int kt = i*64 + kt0;
      const unsigned short* gp = qbase + (size_t)kt*1536 + 1024 + h*64 + dg;
      bf16x8 v0 = *(const bf16x8*)gp;
      bf16x8 v1 = *(const bf16x8*)(gp+8);
#pragma unroll
      for(int e=0;e<8;e++){
        int d  = dg+e;
        *(unsigned short*)((char*)sVT + d*512  + ((kt*2) ^ ((d&7)<<4)))  = (unsigned short)v0[e];
        int d2 = dg+8+e;
        *(unsigned short*)((char*)sVT + d2*512 + ((kt*2) ^ ((d2&7)<<4))) = (unsigned short)v1[e];
      }
    }
  }
  bf16x8 qf[2];
  {
    const unsigned short* qrow = qbase + (size_t)(q0 + w*16 + (l&15))*1536 + h*64;
    qf[0] = *(const bf16x8*)(qrow + ((l>>4)<<3));
    qf[1] = *(const bf16x8*)(qrow + ((l>>4)<<3) + 32);
  }
  __syncthreads();

  f32x4 sacc[16];
#pragma unroll
  for(int kb=0;kb<16;kb++) sacc[kb] = (f32x4){0.f,0.f,0.f,0.f};
#pragma unroll
  for(int kb=0;kb<16;kb++){
    int rk = kb*16 + (l&15);
#pragma unroll
    for(int ks=0;ks<2;ks++){
      bf16x8 kf = *(const bf16x8*)((const char*)sK + rk*128 + (((((l>>4)<<4)|(ks<<6))) ^ ((rk&7)<<4)));
      sacc[kb] = __builtin_amdgcn_mfma_f32_16x16x32_bf16(qf[ks], kf, sacc[kb], 0, 0, 0);
    }
  }
  float rden[4];
#pragma unroll
  for(int j=0;j<4;j++){
    float m = -1e38f;
#pragma unroll
    for(int kb=0;kb<16;kb++) m = fmaxf(m, sacc[kb][j]);
#pragma unroll
    for(int o=1;o<16;o<<=1) m = fmaxf(m, __shfl_xor(m,o,64));
    m *= 0.125f;
    float s = 0.f;
#pragma unroll
    for(int kb=0;kb<16;kb++){
      float e = expf(sacc[kb][j]*0.125f - m);
      sacc[kb][j] = e; s += e;
    }
#pragma unroll
    for(int o=1;o<16;o<<=1) s += __shfl_xor(s,o,64);
    rden[j] = 1.f/s;
  }
  __syncthreads();

  char* sP = (char*)sK + w*8192;
#pragma unroll
  for(int kb=0;kb<16;kb++){
    int k = kb*16 + (l&15);
#pragma unroll
    for(int j=0;j<4;j++){
      int qr = ((l>>4)<<2) + j;
      *(unsigned short*)(sP + qr*512 + ((k*2) ^ ((qr&7)<<4))) = bfr(sacc[kb][j]);
    }
  }
  __syncthreads();

  f32x4 oacc[4];
#pragma unroll
  for(int df=0;df<4;df++) oacc[df] = (f32x4){0.f,0.f,0.f,0.f};
#pragma unroll
  for(int kstep=0;kstep<8;kstep++){
    bf16x8 pa = *(const bf16x8*)(sP + (l&15)*512 + ((((kstep<<6)|((l>>4)<<4))) ^ ((l&7)<<4)));
#pragma unroll
    for(int df=0;df<4;df++){
      int d = df*16 + (l&15);
      bf16x8 vb = *(const bf16x8*)((char*)sVT + d*512 + ((((kstep<<6)|((l>>4)<<4))) ^ ((d&7)<<4)));
      oacc[df] = __builtin_amdgcn_mfma_f32_16x16x32_bf16(pa, vb, oacc[df], 0, 0, 0);
    }
  }
  int orow0 = b*SS + q0 + w*16 + ((l>>4)<<2);
#pragma unroll
  for(int df=0;df<4;df++){
    int col = h*64 + df*16 + (l&15);
#pragma unroll
    for(int j=0;j<4;j++)
      attno[(size_t)(orow0+j)*DD + col] = bfr(oacc[df][j]*rden[j]);
  }
}

// ---------------- lm_head: 256x256 tile, 512 threads, 8 waves (2x4), BK=64 ----------------
__global__ __launch_bounds__(512)
void k_lmgemm(const unsigned short* __restrict__ A, const unsigned short* __restrict__ W,
              const float* __restrict__ bias, float* __restrict__ C){
  __shared__ unsigned short sA[2*256*64];  // 64KB
  __shared__ unsigned short sW[2*256*64];  // 64KB
  int t = threadIdx.x, lane = t & 63, w = t >> 6;
  int wr = w >> 2, wc = w & 3;
  int rowbase = blockIdx.y*256, colbase = blockIdx.z*256;
  int sr = t >> 3, ss8 = t & 7;

  f32x4 acc[8][4];
#pragma unroll
  for(int m=0;m<8;m++)
#pragma unroll
    for(int n=0;n<4;n++) acc[m][n] = (f32x4){0.f,0.f,0.f,0.f};

  auto STAGE = [&](int buf, int k0){
    unsigned short* dA = sA + buf*16384;
    unsigned short* dW = sW + buf*16384;
#pragma unroll
    for(int i = 0; i < 4; i++){
      int r  = i*64 + sr;
      int ce = ((ss8<<4) ^ ((r&7)<<4)) >> 1;
      const unsigned short* gp = A + (size_t)(rowbase + r)*DD + k0 + ce;
      __builtin_amdgcn_global_load_lds((const __attribute__((address_space(1))) void*)gp,
          (__attribute__((address_space(3))) void*)(dA + i*4096 + t*8), 16, 0, 0);
      const unsigned short* gw = W + (size_t)(colbase + r)*DD + k0 + ce;
      __builtin_amdgcn_global_load_lds((const __attribute__((address_space(1))) void*)gw,
          (__attribute__((address_space(3))) void*)(dW + i*4096 + t*8), 16, 0, 0);
    }
  };

  STAGE(0, 0);
  int cur = 0;
  for(int k0 = 0; k0 < DD; k0 += 64){
    if(k0 + 64 < DD){
      STAGE(cur^1, k0+64);
      asm volatile("s_waitcnt vmcnt(8)" ::: "memory");
    } else {
      asm volatile("s_waitcnt vmcnt(0)" ::: "memory");
    }
    __builtin_amdgcn_s_barrier();
    __builtin_amdgcn_sched_barrier(0);
    const char* bA = (const char*)(sA + cur*16384);
    const char* bW = (const char*)(sW + cur*16384);
#pragma unroll
    for(int ks = 0; ks < 2; ks++){
      bf16x8 af[8], wf[4];
#pragma unroll
      for(int m = 0; m < 8; m++){
        int r = wr*128 + m*16 + (lane & 15);
        af[m] = *(const bf16x8*)(bA + r*128 + (((((lane>>4)<<4)|(ks<<6))) ^ ((r&7)<<4)));
      }
#pragma unroll
      for(int n = 0; n < 4; n++){
        int r = wc*64 + n*16 + (lane & 15);
        wf[n] = *(const bf16x8*)(bW + r*128 + (((((lane>>4)<<4)|(ks<<6))) ^ ((r&7)<<4)));
      }
#pragma unroll
      for(int m = 0; m < 8; m++)
#pragma unroll
        for(int n = 0; n < 4; n++)
          acc[m][n] = __builtin_amdgcn_mfma_f32_16x16x32_bf16(af[m], wf[n], acc[m][n], 0, 0, 0);
    }
    asm volatile("s_waitcnt lgkmcnt(0)" ::: "memory");
    __builtin_amdgcn_s_barrier();
    cur ^= 1;
  }
  int orow0 = rowbase + wr*128 + ((lane >> 4) << 2);
  int ocol0 = colbase + wc*64 + (lane & 15);
#pragma unroll
  for(int m = 0; m < 8; m++){
#pragma unroll
    for(int n = 0; n < 4; n++){
      int col = ocol0 + n*16;
      float bv = bias[col];
#pragma unroll
      for(int j = 0; j < 4; j++){
        int row = orow0 + m*16 + j;
        C[(size_t)row*VV + col] = acc[m][n][j] + bv;
      }
    }
  }
}

// ---------------- host launcher ----------------
extern "C" void kernel_launch(void* const* d_in, const int* in_sizes, int n_in,
                              void* d_out, int out_size, void* d_ws, size_t ws_size,
                              hipStream_t stream){
  const int*   ids   = (const int*)d_in[0];
  const float* emb   = (const float*)d_in[1];
  const float* r_w1  = (const float*)d_in[2];
  const float* r_b1  = (const float*)d_in[3];
  const float* r_w2  = (const float*)d_in[4];
  const float* r_b2  = (const float*)d_in[5];
  const float* r_q   = (const float*)d_in[6];
  const float* in_w  = (const float*)d_in[7];
  const float* in_b  = (const float*)d_in[8];
  const float* out_w = (const float*)d_in[9];
  const float* out_b = (const float*)d_in[10];
  const float* gate_w= (const float*)d_in[11];
  const float* gate_b= (const float*)d_in[12];
  const float* f_w1  = (const float*)d_in[13];
  const float* f_b1  = (const float*)d_in[14];
  const float* f_w2  = (const float*)d_in[15];
  const float* f_b2  = (const float*)d_in[16];
  const float* tag   = (const float*)d_in[17];
  const float* lm_w  = (const float*)d_in[18];
  const float* lm_b  = (const float*)d_in[19];
  float* out = (float*)d_out;
  float* ws  = (float*)d_ws;

  const size_t M = (size_t)TOK*DD;   // 1,048,576
  float* x0     = ws;            // ping
  float* x1     = ws + 1*M;      // pong
  float* z      = ws + 2*M;
  float* gtmp   = ws + 3*M;
  float* P0     = ws + 4*M;
  float* P1     = ws + 5*M;
  float* psum   = ws + 6*M;      // 65536 f32
  int*   ipool  = (int*)(ws + 6*M + 65536);
  int* action = ipool; int* dof = ipool+BB; int* active = ipool+2*BB; int* visits = ipool+3*BB;

  unsigned short* ub = (unsigned short*)(ws + 6*M + 65536 + 64);
  unsigned short* z_bf     = ub;
  unsigned short* z2_bf    = ub + 1*M;
  unsigned short* attno_bf = ub + 2*M;
  unsigned short* qkv_bf   = ub + 3*M;    // 3M
  unsigned short* ffh_bf   = ub + 6*M;    // 4M
  unsigned short* wb = ub + 10*M;
  unsigned short* in_wb   = wb;
  unsigned short* out_wb  = in_wb  + (size_t)EE*LL*3*DD*DD;
  unsigned short* gate_wb = out_wb + (size_t)EE*LL*DD*DD;
  unsigned short* f_w1b   = gate_wb+ (size_t)EE*LL*DD*2*DD;
  unsigned short* f_w2b   = f_w1b  + (size_t)EE*LL*FFF*DD;
  unsigned short* lm_wb   = f_w2b  + (size_t)EE*LL*DD*FFF;

  k_preproc<<<CASTBLK+TOK,256,0,stream>>>(in_w,out_w,gate_w,f_w1,f_w2,lm_w,
                                          in_wb,out_wb,gate_wb,f_w1b,f_w2b,lm_wb,
                                          ids, emb, x0);

  float* xc = x0;
  for(int step=0; step<3; step++){
    float* xn = (xc==x0) ? x1 : x0;
    if(step==0)
      k_lnpsum<<<TOK+128,256,0,stream>>>(xc, nullptr, nullptr, xn, z, z_bf, psum, dof);
    else{
      k_lnpsum<<<TOK+128,256,0,stream>>>(xc, P0, P1, xn, z, z_bf, psum, dof);
      xc = xn;
    }
    k_router<<<BB,256,0,stream>>>(psum,r_w1,r_b1,r_w2,r_b2,r_q,action,dof,visits,active,step);
    for(int l=0; l<LL; l++){
      if(l==1){
        float* xn2 = (xc==x0) ? x1 : x0;
        k_lnpsum<<<TOK,256,0,stream>>>(xc, P0, P1, xn2, z, z_bf, nullptr, dof);
        xc = xn2;
      }
      k_qkvgate<<<dim3(BB,4,16),256,0,stream>>>(z_bf, in_wb,in_b, gate_wb,gate_b,
                                                qkv_bf, gtmp, l, action, dof);
      k_attn<<<dim3(BB*NHH,4),256,0,stream>>>(qkv_bf, attno_bf, dof);
      k_outgate<<<TOK/16,256,0,stream>>>(attno_bf, out_wb, out_b, gate_wb,
                                         gtmp, z, xc, z2_bf, l, action, dof);
      k_ffn1<<<dim3(BB,4,16),256,0,stream>>>(z2_bf, f_w1b,f_b1, ffh_bf, l, action, dof);
      k_ffn2<<<dim3(BB,4,8),256,0,stream>>>(ffh_bf, f_w2b,f_b2, tag, P0, P1, l, action, dof);
    }
  }

  {
    float* xn = (xc==x0) ? x1 : x0;
    k_lnpsum<<<TOK,256,0,stream>>>(xc, P0, P1, xn, z, z_bf, nullptr, dof);
  }
  k_lmgemm<<<dim3(1,8,VV/256),512,0,stream>>>(z_bf, lm_wb, lm_b, out);
}

// Round 8
// 730.269 us; speedup vs baseline: 1.1811x; 1.1811x over previous
//
#include <hip/hip_runtime.h>
#include <hip/hip_bf16.h>
#include <math.h>

#define BB   8
#define SS   256
#define DD   512
#define NHH  8
#define HDD  64
#define EE   4
#define LL   2
#define FFF  2048
#define RHH  256
#define VV   32000
#define MVV  2
#define TOK  (BB*SS)   // 2048
#define CASTBLK 44672

typedef __attribute__((ext_vector_type(8))) short bf16x8;
typedef __attribute__((ext_vector_type(4))) float f32x4;

// ---------------- helpers ----------------
__device__ __forceinline__ float wred_sum(float v){
#pragma unroll
  for(int o=32;o;o>>=1) v += __shfl_xor(v,o,64);
  return v;
}
__device__ __forceinline__ float block_sum(float v, float* sh){
  v = wred_sum(v);
  if((threadIdx.x&63)==0) sh[threadIdx.x>>6]=v;
  __syncthreads();
  float t = sh[0]+sh[1]+sh[2]+sh[3];
  __syncthreads();
  return t;
}
__device__ __forceinline__ float gelu_exact(float x){
  return 0.5f*x*(1.f+erff(x*0.70710678118654752f));
}
__device__ __forceinline__ unsigned short bfr(float f){
  union{float f; unsigned u;} c; c.f=f;
  unsigned u = c.u;
  return (unsigned short)((u + 0x7FFFu + ((u>>16)&1u)) >> 16);
}
__device__ __forceinline__ float bff(unsigned short u){
  union{unsigned u; float f;} c; c.u = ((unsigned)u)<<16; return c.f;
}

// ---------------- fused: weight casts + embed+PE+LN ----------------
__global__ void k_preproc(const float* __restrict__ s0,const float* __restrict__ s1,
                          const float* __restrict__ s2,const float* __restrict__ s3,
                          const float* __restrict__ s4,const float* __restrict__ s5,
                          unsigned short* __restrict__ d0,unsigned short* __restrict__ d1,
                          unsigned short* __restrict__ d2,unsigned short* __restrict__ d3,
                          unsigned short* __restrict__ d4,unsigned short* __restrict__ d5,
                          const int* __restrict__ ids, const float* __restrict__ emb,
                          float* __restrict__ x){
  __shared__ float sh[4];
  if(blockIdx.x < CASTBLK){
    long i = (long)blockIdx.x*256 + threadIdx.x;
    const float* s; unsigned short* d; long o;
    if(i < 1572864L){ s=s0; d=d0; o=i; }
    else if(i < 2097152L){ s=s1; d=d1; o=i-1572864L; }
    else if(i < 3145728L){ s=s2; d=d2; o=i-2097152L; }
    else if(i < 5242880L){ s=s3; d=d3; o=i-3145728L; }
    else if(i < 7340032L){ s=s4; d=d4; o=i-5242880L; }
    else { s=s5; d=d5; o=i-7340032L; }
    float4 v = ((const float4*)s)[o];
    ushort4 u; u.x=bfr(v.x); u.y=bfr(v.y); u.z=bfr(v.z); u.w=bfr(v.w);
    ((ushort4*)d)[o] = u;
    return;
  }
  int tok = blockIdx.x - CASTBLK;
  int s = tok & (SS-1);
  int tid = threadIdx.x;
  int id = ids[tok];
  float v[2];
#pragma unroll
  for(int i=0;i<2;i++){
    int d = tid + i*256;
    float e = emb[(size_t)id*DD + d] * 22.627416997969522f; // sqrt(512)
    int j = d >> 1;
    float freq = expf((float)(2*j) * (-0.0179889460390160f)); // -ln(1e4)/512
    float arg = (float)s * freq;
    v[i] = e + ((d & 1) ? cosf(arg) : sinf(arg));
  }
  float m = block_sum(v[0]+v[1], sh) * (1.f/DD);
  float dd0=v[0]-m, dd1=v[1]-m;
  float var = block_sum(dd0*dd0+dd1*dd1, sh) * (1.f/DD);
  float inv = rsqrtf(var + 1e-5f);
  float* q = x + (size_t)tok*DD;
  q[tid] = dd0*inv; q[tid+256] = dd1*inv;
}

// ---------------- combine(+x ping-pong) + LN(bf16 out) + optional psum ----------------
__global__ void k_lnpsum(const float* __restrict__ xin, const float* __restrict__ P0,
                         const float* __restrict__ P1, float* __restrict__ xout,
                         unsigned short* __restrict__ zb,
                         float* __restrict__ psum, const int* __restrict__ dof){
  __shared__ float sh[4];
  int tid = threadIdx.x;
  if(blockIdx.x < TOK){
    int tok = blockIdx.x; int b = tok>>8;
    size_t base = (size_t)tok*DD;
    float a0 = xin[base+tid], a1 = xin[base+tid+256];
    if(P0){
      if(dof[b]){
        a0 += P0[base+tid]     + P1[base+tid];
        a1 += P0[base+tid+256] + P1[base+tid+256];
      }
      xout[base+tid] = a0; xout[base+tid+256] = a1;
    }
    float m = block_sum(a0+a1, sh) * (1.f/DD);
    float d0=a0-m, d1=a1-m;
    float var = block_sum(d0*d0+d1*d1, sh) * (1.f/DD);
    float inv = rsqrtf(var + 1e-5f);
    zb[base+tid] = bfr(d0*inv); zb[base+tid+256] = bfr(d1*inv);
  } else {
    int pb = blockIdx.x - TOK; int b = pb>>4, p = pb&15;
    bool c = (P0 != nullptr) && dof[b];
    float s0=0.f, s1=0.f;
    for(int tt=0; tt<16; tt++){
      size_t r = (size_t)(b*SS + p*16 + tt)*DD;
      float v0 = xin[r+tid], v1 = xin[r+tid+256];
      if(c){ v0 += P0[r+tid]+P1[r+tid]; v1 += P0[r+tid+256]+P1[r+tid+256]; }
      s0 += v0; s1 += v1;
    }
    float* q = psum + (size_t)(b*16+p)*DD;
    q[tid] = s0; q[tid+256] = s1;
  }
}

// ---------------- router (reduces psum partials) ----------------
__global__ void k_router(const float* __restrict__ psum,
                         const float* __restrict__ r_w1, const float* __restrict__ r_b1,
                         const float* __restrict__ r_w2, const float* __restrict__ r_b2,
                         const float* __restrict__ r_q,
                         int* __restrict__ action, int* __restrict__ dof,
                         int* __restrict__ visits, int* __restrict__ active, int step){
  int b = blockIdx.x; int tid = threadIdx.x;
  if(step==0 && tid==0){ active[b]=1; for(int e=0;e<EE;e++) visits[b*EE+e]=0; }
  __shared__ float ssum[DD];
  __shared__ float hid[RHH];
  __shared__ float lg[EE+1];
  float s0=0.f, s1=0.f;
  for(int p=0;p<16;p++){
    const float* q = psum + (size_t)(b*16+p)*DD;
    s0 += q[tid]; s1 += q[tid+256];
  }
  ssum[tid] = s0*(1.f/SS); ssum[tid+256] = s1*(1.f/SS);
  __syncthreads();
  float acc = r_b1[tid];
  const float4* wr4 = (const float4*)(r_w1 + (size_t)tid*DD);
  for(int d4=0; d4<DD/4; d4++){
    float4 wv = wr4[d4];
    float4 sv = *(const float4*)&ssum[d4*4];
    acc += wv.x*sv.x + wv.y*sv.y + wv.z*sv.z + wv.w*sv.w;
  }
  hid[tid] = gelu_exact(acc);
  __syncthreads();
  if(tid < EE+1){
    const float* w2 = r_w2 + (size_t)tid*RHH;
    float a = r_b2[tid] + r_q[tid];
    for(int j=0;j<RHH;j++) a += hid[j]*w2[j];
    lg[tid]=a;
  }
  __syncthreads();
  if(tid==0){
    float m=0.f; for(int k=0;k<EE+1;k++) m+=lg[k]; m *= (1.f/(EE+1));
    float v=0.f; for(int k=0;k<EE+1;k++){float d=lg[k]-m; v+=d*d;} v *= (1.f/(EE+1));
    float inv = rsqrtf(v+1e-5f);
    float best=-1e38f; int bi=0;
    for(int k=0;k<EE+1;k++){
      float fl = (lg[k]-m)*inv;
      fl = fminf(fmaxf(fl,-10.f),10.f);
      if(k<EE && visits[b*EE+k]>=MVV) fl = -1e38f;
      if(fl > best){best=fl; bi=k;}
    }
    int dd = (active[b] && bi<EE) ? 1 : 0;
    action[b]=bi; dof[b]=dd;
    if(dd) visits[b*EE+bi]++;
    active[b]=dd;
  }
}

// ---------------- generic 64x128 MFMA GEMM core, BK=64, 2-phase dbuf ----------------
template<int EPI>
__device__ __forceinline__ void mg64(
    unsigned short* sA, unsigned short* sW,
    const unsigned short* __restrict__ A, int Ald,
    const unsigned short* __restrict__ W, int Wld,
    const float* __restrict__ bias, const float* __restrict__ tagv,
    int N, int K,
    float* __restrict__ Cf, unsigned short* __restrict__ Cb,
    int rowbase, int colbase){
  int t = threadIdx.x;
  int lane = t & 63;
  int w = t >> 6;
  int wcol0 = w*32;
  int sr = t >> 3, ss8 = t & 7;

  f32x4 acc[4][2];
#pragma unroll
  for(int m=0;m<4;m++)
#pragma unroll
    for(int n=0;n<2;n++) acc[m][n] = (f32x4){0.f,0.f,0.f,0.f};

  auto STAGE = [&](int buf, int k0){
    unsigned short* dA = sA + buf*4096;
    unsigned short* dW = sW + buf*8192;
#pragma unroll
    for(int i = 0; i < 2; i++){
      int r  = i*32 + sr;
      int ce = ((ss8<<4) ^ ((r&7)<<4)) >> 1;
      const unsigned short* gp = A + (size_t)(rowbase + r)*Ald + k0 + ce;
      __builtin_amdgcn_global_load_lds((const __attribute__((address_space(1))) void*)gp,
          (__attribute__((address_space(3))) void*)(dA + i*2048 + t*8), 16, 0, 0);
    }
#pragma unroll
    for(int i = 0; i < 4; i++){
      int r  = i*32 + sr;
      int ce = ((ss8<<4) ^ ((r&7)<<4)) >> 1;
      const unsigned short* gw = W + (size_t)(colbase + r)*Wld + k0 + ce;
      __builtin_amdgcn_global_load_lds((const __attribute__((address_space(1))) void*)gw,
          (__attribute__((address_space(3))) void*)(dW + i*2048 + t*8), 16, 0, 0);
    }
  };

  STAGE(0, 0);
  int cur = 0;
  for(int k0 = 0; k0 < K; k0 += 64){
    if(k0 + 64 < K){
      STAGE(cur^1, k0+64);
      asm volatile("s_waitcnt vmcnt(6)" ::: "memory");
    } else {
      asm volatile("s_waitcnt vmcnt(0)" ::: "memory");
    }
    __builtin_amdgcn_s_barrier();
    __builtin_amdgcn_sched_barrier(0);
    const char* bA = (const char*)(sA + cur*4096);
    const char* bW = (const char*)(sW + cur*8192);
#pragma unroll
    for(int ks = 0; ks < 2; ks++){
      bf16x8 af[4], wf[2];
#pragma unroll
      for(int m = 0; m < 4; m++){
        int r = m*16 + (lane & 15);
        af[m] = *(const bf16x8*)(bA + r*128 + (((((lane>>4)<<4)|(ks<<6))) ^ ((r&7)<<4)));
      }
#pragma unroll
      for(int n = 0; n < 2; n++){
        int r = wcol0 + n*16 + (lane & 15);
        wf[n] = *(const bf16x8*)(bW + r*128 + (((((lane>>4)<<4)|(ks<<6))) ^ ((r&7)<<4)));
      }
#pragma unroll
      for(int m = 0; m < 4; m++)
#pragma unroll
        for(int n = 0; n < 2; n++)
          acc[m][n] = __builtin_amdgcn_mfma_f32_16x16x32_bf16(af[m], wf[n], acc[m][n], 0, 0, 0);
    }
    asm volatile("s_waitcnt lgkmcnt(0)" ::: "memory");
    __builtin_amdgcn_s_barrier();
    cur ^= 1;
  }
  int orow0 = rowbase + ((lane >> 4) << 2);
  int ocol0 = colbase + wcol0 + (lane & 15);
#pragma unroll
  for(int m = 0; m < 4; m++){
#pragma unroll
    for(int n = 0; n < 2; n++){
      int col = ocol0 + n*16;
      float addv = (bias ? bias[col] : 0.f) + (tagv ? tagv[col] : 0.f);
#pragma unroll
      for(int j = 0; j < 4; j++){
        int row = orow0 + m*16 + j;
        size_t idx = (size_t)row*N + col;
        float v = acc[m][n][j] + addv;
        if(EPI == 0){ if(Cf) Cf[idx] = v; if(Cb) Cb[idx] = bfr(v); }
        else if(EPI == 1){ Cb[idx] = bfr(gelu_exact(v)); }
        else { Cf[idx] += v; }
      }
    }
  }
}

#define GEMM_LDS __shared__ unsigned short sA[2*64*64]; __shared__ unsigned short sW[2*128*64];

// qkv (z<12) + gate z-half (z>=12), both read z_bf, K=512
__global__ __launch_bounds__(256)
void k_qkvgate(const unsigned short* __restrict__ z_bf,
               const unsigned short* __restrict__ in_wb, const float* __restrict__ in_b,
               const unsigned short* __restrict__ gate_wb, const float* __restrict__ gate_b,
               unsigned short* __restrict__ qkv_bf, float* __restrict__ gtmp, int l,
               const int* __restrict__ action, const int* __restrict__ dof){
  GEMM_LDS
  int b = blockIdx.x; if(!dof[b]) return;
  size_t o = (size_t)(action[b]*LL + l);
  int rowbase = b*SS + blockIdx.y*64;
  int zz = blockIdx.z;
  if(zz < 12){
    mg64<0>(sA,sW, z_bf,DD, in_wb + o*3*DD*DD, DD, in_b + o*3*DD, nullptr,
            3*DD, DD, nullptr, qkv_bf, rowbase, zz*128);
  } else {
    mg64<0>(sA,sW, z_bf,DD, gate_wb + o*DD*2*DD, 2*DD, gate_b + o*DD, nullptr,
            DD, DD, gtmp, nullptr, rowbase, (zz-12)*128);
  }
}

// out-proj: ao_bf = attno @ out_w^T + b (bf16 only)
__global__ __launch_bounds__(256)
void k_out(const unsigned short* __restrict__ attno_bf,
           const unsigned short* __restrict__ out_wb, const float* __restrict__ out_b,
           unsigned short* __restrict__ ao_bf, int l,
           const int* __restrict__ action, const int* __restrict__ dof){
  GEMM_LDS
  int b = blockIdx.x; if(!dof[b]) return;
  size_t o = (size_t)(action[b]*LL + l);
  mg64<0>(sA,sW, attno_bf,DD, out_wb + o*DD*DD, DD, out_b + o*DD, nullptr,
          DD, DD, nullptr, ao_bf, b*SS + blockIdx.y*64, blockIdx.z*128);
}

// gate ao-half: gtmp += ao @ gate_w[:,512:]^T
__global__ __launch_bounds__(256)
void k_gateao(const unsigned short* __restrict__ ao_bf,
              const unsigned short* __restrict__ gate_wb,
              float* __restrict__ gtmp, int l,
              const int* __restrict__ action, const int* __restrict__ dof){
  GEMM_LDS
  int b = blockIdx.x; if(!dof[b]) return;
  size_t o = (size_t)(action[b]*LL + l);
  mg64<2>(sA,sW, ao_bf,DD, gate_wb + o*DD*2*DD + 512, 2*DD, nullptr, nullptr,
          DD, DD, gtmp, nullptr, b*SS + blockIdx.y*64, blockIdx.z*128);
}

// ffn1: ffh = gelu(z2 @ w1^T + b1)
__global__ __launch_bounds__(256)
void k_ffn1(const unsigned short* __restrict__ z2_bf,
            const unsigned short* __restrict__ f_w1b, const float* __restrict__ f_b1,
            unsigned short* __restrict__ ffh_bf, int l,
            const int* __restrict__ action, const int* __restrict__ dof){
  GEMM_LDS
  int b = blockIdx.x; if(!dof[b]) return;
  size_t o = (size_t)(action[b]*LL + l);
  mg64<1>(sA,sW, z2_bf,DD, f_w1b + o*FFF*DD, DD, f_b1 + o*FFF, nullptr,
          FFF, DD, nullptr, ffh_bf, b*SS + blockIdx.y*64, blockIdx.z*128);
}

// ffn2 split-K: half 0 -> P0 (+bias +tag at l==1), half 1 -> P1
__global__ __launch_bounds__(256)
void k_ffn2(const unsigned short* __restrict__ ffh_bf,
            const unsigned short* __restrict__ f_w2b, const float* __restrict__ f_b2,
            const float* __restrict__ tag,
            float* __restrict__ P0, float* __restrict__ P1, int l,
            const int* __restrict__ action, const int* __restrict__ dof){
  GEMM_LDS
  int b = blockIdx.x; if(!dof[b]) return;
  size_t o = (size_t)(action[b]*LL + l);
  int half = blockIdx.z >> 2, colb = (blockIdx.z & 3)*128;
  const float* bias = half ? nullptr : (f_b2 + o*DD);
  const float* tagv = (half==0 && l==LL-1) ? (tag + (size_t)action[b]*DD) : nullptr;
  mg64<0>(sA,sW, ffh_bf + half*1024, FFF, f_w2b + o*DD*FFF + half*1024, FFF,
          bias, tagv, DD, 1024, half ? P1 : P0, nullptr,
          b*SS + blockIdx.y*64, colb);
}

// ---------------- fused attention: softmax(QK^T/8) @ V, bf16 MFMA ----------------
__global__ __launch_bounds__(256)
void k_attn(const unsigned short* __restrict__ qkv, unsigned short* __restrict__ attno,
            const int* __restrict__ dof){
  int bh = blockIdx.x; int b = bh>>3, h = bh&7;
  if(!dof[b]) return;
  int q0 = blockIdx.y*64;
  __shared__ unsigned short sK[256*64];   // 32KB; reused as P after scores
  __shared__ unsigned short sVT[64*256];  // 32KB, V transposed [d][k]
  int t = threadIdx.x, l = t&63, w = t>>6;
  const unsigned short* qbase = qkv + (size_t)b*SS*1536;

  {
    int sr = t>>3, s8 = t&7;
#pragma unroll
    for(int i=0;i<8;i++){
      int r = i*32 + sr;
      int ce = ((s8<<4) ^ ((r&7)<<4)) >> 1;
      const unsigned short* gp = qbase + (size_t)r*1536 + 512 + h*64 + ce;
      __builtin_amdgcn_global_load_lds((const __attribute__((address_space(1))) void*)gp,
          (__attribute__((address_space(3))) void*)(sK + i*2048 + t*8), 16, 0, 0);
    }
  }
  {
    int kt0 = t>>2, dg = (t&3)*16;
#pragma unroll
    for(int i=0;i<4;i++){
      int kt = i*64 + kt0;
      const unsigned short* gp = qbase + (size_t)kt*1536 + 1024 + h*64 + dg;
      bf16x8 v0 = *(const bf16x8*)gp;
      bf16x8 v1 = *(const bf16x8*)(gp+8);
#pragma unroll
      for(int e=0;e<8;e++){
        int d  = dg+e;
        *(unsigned short*)((char*)sVT + d*512  + ((kt*2) ^ ((d&7)<<4)))  = (unsigned short)v0[e];
        int d2 = dg+8+e;
        *(unsigned short*)((char*)sVT + d2*512 + ((kt*2) ^ ((d2&7)<<4))) = (unsigned short)v1[e];
      }
    }
  }
  bf16x8 qf[2];
  {
    const unsigned short* qrow = qbase + (size_t)(q0 + w*16 + (l&15))*1536 + h*64;
    qf[0] = *(const bf16x8*)(qrow + ((l>>4)<<3));
    qf[1] = *(const bf16x8*)(qrow + ((l>>4)<<3) + 32);
  }
  __syncthreads();

  f32x4 sacc[16];
#pragma unroll
  for(int kb=0;kb<16;kb++) sacc[kb] = (f32x4){0.f,0.f,0.f,0.f};
#pragma unroll
  for(int kb=0;kb<16;kb++){
    int rk = kb*16 + (l&15);
#pragma unroll
    for(int ks=0;ks<2;ks++){
      bf16x8 kf = *(const bf16x8*)((const char*)sK + rk*128 + (((((l>>4)<<4)|(ks<<6))) ^ ((rk&7)<<4)));
      sacc[kb] = __builtin_amdgcn_mfma_f32_16x16x32_bf16(qf[ks], kf, sacc[kb], 0, 0, 0);
    }
  }
  float rden[4];
#pragma unroll
  for(int j=0;j<4;j++){
    float m = -1e38f;
#pragma unroll
    for(int kb=0;kb<16;kb++) m = fmaxf(m, sacc[kb][j]);
#pragma unroll
    for(int o=1;o<16;o<<=1) m = fmaxf(m, __shfl_xor(m,o,64));
    m *= 0.125f;
    float s = 0.f;
#pragma unroll
    for(int kb=0;kb<16;kb++){
      float e = expf(sacc[kb][j]*0.125f - m);
      sacc[kb][j] = e; s += e;
    }
#pragma unroll
    for(int o=1;o<16;o<<=1) s += __shfl_xor(s,o,64);
    rden[j] = 1.f/s;
  }
  __syncthreads();

  char* sP = (char*)sK + w*8192;
#pragma unroll
  for(int kb=0;kb<16;kb++){
    int k = kb*16 + (l&15);
#pragma unroll
    for(int j=0;j<4;j++){
      int qr = ((l>>4)<<2) + j;
      *(unsigned short*)(sP + qr*512 + ((k*2) ^ ((qr&7)<<4))) = bfr(sacc[kb][j]);
    }
  }
  __syncthreads();

  f32x4 oacc[4];
#pragma unroll
  for(int df=0;df<4;df++) oacc[df] = (f32x4){0.f,0.f,0.f,0.f};
#pragma unroll
  for(int kstep=0;kstep<8;kstep++){
    bf16x8 pa = *(const bf16x8*)(sP + (l&15)*512 + ((((kstep<<6)|((l>>4)<<4))) ^ ((l&7)<<4)));
#pragma unroll
    for(int df=0;df<4;df++){
      int d = df*16 + (l&15);
      bf16x8 vb = *(const bf16x8*)((char*)sVT + d*512 + ((((kstep<<6)|((l>>4)<<4))) ^ ((d&7)<<4)));
      oacc[df] = __builtin_amdgcn_mfma_f32_16x16x32_bf16(pa, vb, oacc[df], 0, 0, 0);
    }
  }
  int orow0 = b*SS + q0 + w*16 + ((l>>4)<<2);
#pragma unroll
  for(int df=0;df<4;df++){
    int col = h*64 + df*16 + (l&15);
#pragma unroll
    for(int j=0;j<4;j++)
      attno[(size_t)(orow0+j)*DD + col] = bfr(oacc[df][j]*rden[j]);
  }
}

// ---------------- gated residual + LN2 fused (x in-place, bf16 z/ao inputs) ----------------
__global__ void k_gateres_ln(const unsigned short* __restrict__ zb,
                             const unsigned short* __restrict__ aob,
                             const float* __restrict__ g, float* __restrict__ x,
                             unsigned short* __restrict__ z2b, const int* __restrict__ dof){
  int tok = blockIdx.x; if(!dof[tok>>8]) return;
  __shared__ float sh[4];
  int tid=threadIdx.x;
  size_t base=(size_t)tok*DD;
  float zz0=bff(zb[base+tid]),     aa0=bff(aob[base+tid]),     gg0=g[base+tid];
  float zz1=bff(zb[base+tid+256]), aa1=bff(aob[base+tid+256]), gg1=g[base+tid+256];
  float t0 = zz0 + aa0/(1.f+expf(-gg0));
  float t1 = zz1 + aa1/(1.f+expf(-gg1));
  float m = block_sum(t0+t1,sh)*(1.f/DD);
  float d0=t0-m, d1=t1-m;
  float var=block_sum(d0*d0+d1*d1,sh)*(1.f/DD);
  float inv=rsqrtf(var+1e-5f);
  float xn0 = x[base+tid]     + d0*inv;
  float xn1 = x[base+tid+256] + d1*inv;
  x[base+tid] = xn0; x[base+tid+256] = xn1;
  float m2 = block_sum(xn0+xn1,sh)*(1.f/DD);
  float e0=xn0-m2, e1=xn1-m2;
  float var2=block_sum(e0*e0+e1*e1,sh)*(1.f/DD);
  float inv2=rsqrtf(var2+1e-5f);
  z2b[base+tid] = bfr(e0*inv2); z2b[base+tid+256] = bfr(e1*inv2);
}

// ---------------- lm_head: 256x256 tile, 512 threads, 8 waves (2x4), BK=64 ----------------
__global__ __launch_bounds__(512)
void k_lmgemm(const unsigned short* __restrict__ A, const unsigned short* __restrict__ W,
              const float* __restrict__ bias, float* __restrict__ C){
  __shared__ unsigned short sA[2*256*64];  // 64KB
  __shared__ unsigned short sW[2*256*64];  // 64KB
  int t = threadIdx.x, lane = t & 63, w = t >> 6;
  int wr = w >> 2, wc = w & 3;
  int rowbase = blockIdx.y*256, colbase = blockIdx.z*256;
  int sr = t >> 3, ss8 = t & 7;

  f32x4 acc[8][4];
#pragma unroll
  for(int m=0;m<8;m++)
#pragma unroll
    for(int n=0;n<4;n++) acc[m][n] = (f32x4){0.f,0.f,0.f,0.f};

  auto STAGE = [&](int buf, int k0){
    unsigned short* dA = sA + buf*16384;
    unsigned short* dW = sW + buf*16384;
#pragma unroll
    for(int i = 0; i < 4; i++){
      int r  = i*64 + sr;
      int ce = ((ss8<<4) ^ ((r&7)<<4)) >> 1;
      const unsigned short* gp = A + (size_t)(rowbase + r)*DD + k0 + ce;
      __builtin_amdgcn_global_load_lds((const __attribute__((address_space(1))) void*)gp,
          (__attribute__((address_space(3))) void*)(dA + i*4096 + t*8), 16, 0, 0);
      const unsigned short* gw = W + (size_t)(colbase + r)*DD + k0 + ce;
      __builtin_amdgcn_global_load_lds((const __attribute__((address_space(1))) void*)gw,
          (__attribute__((address_space(3))) void*)(dW + i*4096 + t*8), 16, 0, 0);
    }
  };

  STAGE(0, 0);
  int cur = 0;
  for(int k0 = 0; k0 < DD; k0 += 64){
    if(k0 + 64 < DD){
      STAGE(cur^1, k0+64);
      asm volatile("s_waitcnt vmcnt(8)" ::: "memory");
    } else {
      asm volatile("s_waitcnt vmcnt(0)" ::: "memory");
    }
    __builtin_amdgcn_s_barrier();
    __builtin_amdgcn_sched_barrier(0);
    const char* bA = (const char*)(sA + cur*16384);
    const char* bW = (const char*)(sW + cur*16384);
#pragma unroll
    for(int ks = 0; ks < 2; ks++){
      bf16x8 af[8], wf[4];
#pragma unroll
      for(int m = 0; m < 8; m++){
        int r = wr*128 + m*16 + (lane & 15);
        af[m] = *(const bf16x8*)(bA + r*128 + (((((lane>>4)<<4)|(ks<<6))) ^ ((r&7)<<4)));
      }
#pragma unroll
      for(int n = 0; n < 4; n++){
        int r = wc*64 + n*16 + (lane & 15);
        wf[n] = *(const bf16x8*)(bW + r*128 + (((((lane>>4)<<4)|(ks<<6))) ^ ((r&7)<<4)));
      }
#pragma unroll
      for(int m = 0; m < 8; m++)
#pragma unroll
        for(int n = 0; n < 4; n++)
          acc[m][n] = __builtin_amdgcn_mfma_f32_16x16x32_bf16(af[m], wf[n], acc[m][n], 0, 0, 0);
    }
    asm volatile("s_waitcnt lgkmcnt(0)" ::: "memory");
    __builtin_amdgcn_s_barrier();
    cur ^= 1;
  }
  int orow0 = rowbase + wr*128 + ((lane >> 4) << 2);
  int ocol0 = colbase + wc*64 + (lane & 15);
#pragma unroll
  for(int m = 0; m < 8; m++){
#pragma unroll
    for(int n = 0; n < 4; n++){
      int col = ocol0 + n*16;
      float bv = bias[col];
#pragma unroll
      for(int j = 0; j < 4; j++){
        int row = orow0 + m*16 + j;
        C[(size_t)row*VV + col] = acc[m][n][j] + bv;
      }
    }
  }
}

// ---------------- host launcher ----------------
extern "C" void kernel_launch(void* const* d_in, const int* in_sizes, int n_in,
                              void* d_out, int out_size, void* d_ws, size_t ws_size,
                              hipStream_t stream){
  const int*   ids   = (const int*)d_in[0];
  const float* emb   = (const float*)d_in[1];
  const float* r_w1  = (const float*)d_in[2];
  const float* r_b1  = (const float*)d_in[3];
  const float* r_w2  = (const float*)d_in[4];
  const float* r_b2  = (const float*)d_in[5];
  const float* r_q   = (const float*)d_in[6];
  const float* in_w  = (const float*)d_in[7];
  const float* in_b  = (const float*)d_in[8];
  const float* out_w = (const float*)d_in[9];
  const float* out_b = (const float*)d_in[10];
  const float* gate_w= (const float*)d_in[11];
  const float* gate_b= (const float*)d_in[12];
  const float* f_w1  = (const float*)d_in[13];
  const float* f_b1  = (const float*)d_in[14];
  const float* f_w2  = (const float*)d_in[15];
  const float* f_b2  = (const float*)d_in[16];
  const float* tag   = (const float*)d_in[17];
  const float* lm_w  = (const float*)d_in[18];
  const float* lm_b  = (const float*)d_in[19];
  float* out = (float*)d_out;
  float* ws  = (float*)d_ws;

  const size_t M = (size_t)TOK*DD;   // 1,048,576
  float* x0     = ws;            // ping
  float* x1     = ws + 1*M;      // pong
  float* gtmp   = ws + 2*M;
  float* P0     = ws + 3*M;
  float* P1     = ws + 4*M;
  float* psum   = ws + 5*M;      // 65536 f32
  int*   ipool  = (int*)(ws + 5*M + 65536);
  int* action = ipool; int* dof = ipool+BB; int* active = ipool+2*BB; int* visits = ipool+3*BB;

  unsigned short* ub = (unsigned short*)(ws + 5*M + 65536 + 64);
  unsigned short* z_bf     = ub;
  unsigned short* z2_bf    = ub + 1*M;
  unsigned short* attno_bf = ub + 2*M;
  unsigned short* ao_bf    = ub + 3*M;
  unsigned short* qkv_bf   = ub + 4*M;    // 3M
  unsigned short* ffh_bf   = ub + 7*M;    // 4M
  unsigned short* wb = ub + 11*M;
  unsigned short* in_wb   = wb;
  unsigned short* out_wb  = in_wb  + (size_t)EE*LL*3*DD*DD;
  unsigned short* gate_wb = out_wb + (size_t)EE*LL*DD*DD;
  unsigned short* f_w1b   = gate_wb+ (size_t)EE*LL*DD*2*DD;
  unsigned short* f_w2b   = f_w1b  + (size_t)EE*LL*FFF*DD;
  unsigned short* lm_wb   = f_w2b  + (size_t)EE*LL*DD*FFF;

  k_preproc<<<CASTBLK+TOK,256,0,stream>>>(in_w,out_w,gate_w,f_w1,f_w2,lm_w,
                                          in_wb,out_wb,gate_wb,f_w1b,f_w2b,lm_wb,
                                          ids, emb, x0);

  float* xc = x0;
  for(int step=0; step<3; step++){
    float* xn = (xc==x0) ? x1 : x0;
    if(step==0)
      k_lnpsum<<<TOK+128,256,0,stream>>>(xc, nullptr, nullptr, xn, z_bf, psum, dof);
    else{
      k_lnpsum<<<TOK+128,256,0,stream>>>(xc, P0, P1, xn, z_bf, psum, dof);
      xc = xn;
    }
    k_router<<<BB,256,0,stream>>>(psum,r_w1,r_b1,r_w2,r_b2,r_q,action,dof,visits,active,step);
    for(int l=0; l<LL; l++){
      if(l==1){
        float* xn2 = (xc==x0) ? x1 : x0;
        k_lnpsum<<<TOK,256,0,stream>>>(xc, P0, P1, xn2, z_bf, nullptr, dof);
        xc = xn2;
      }
      k_qkvgate<<<dim3(BB,4,16),256,0,stream>>>(z_bf, in_wb,in_b, gate_wb,gate_b,
                                                qkv_bf, gtmp, l, action, dof);
      k_attn<<<dim3(BB*NHH,4),256,0,stream>>>(qkv_bf, attno_bf, dof);
      k_out<<<dim3(BB,4,4),256,0,stream>>>(attno_bf, out_wb,out_b, ao_bf, l, action, dof);
      k_gateao<<<dim3(BB,4,4),256,0,stream>>>(ao_bf, gate_wb, gtmp, l, action, dof);
      k_gateres_ln<<<TOK,256,0,stream>>>(z_bf, ao_bf, gtmp, xc, z2_bf, dof);
      k_ffn1<<<dim3(BB,4,16),256,0,stream>>>(z2_bf, f_w1b,f_b1, ffh_bf, l, action, dof);
      k_ffn2<<<dim3(BB,4,8),256,0,stream>>>(ffh_bf, f_w2b,f_b2, tag, P0, P1, l, action, dof);
    }
  }

  {
    float* xn = (xc==x0) ? x1 : x0;
    k_lnpsum<<<TOK,256,0,stream>>>(xc, P0, P1, xn, z_bf, nullptr, dof);
  }
  k_lmgemm<<<dim3(1,8,VV/256),512,0,stream>>>(z_bf, lm_wb, lm_b, out);
}